// Round 16
// baseline (79.911 us; speedup 1.0000x reference)
//
#include <hip/hip_runtime.h>
#include <stdint.h>

#define BB 64
#define CC 3
#define HH 512
#define WW 512
#define TL 16        // 16x16 tile per WAVE
#define MAXBH 26     // bh <= 26 at scale=1 (15*sqrt2 + 4)
#define MAXBW 28     // bw <= 26 (no alignment loss); stride 28 keeps 16B rows
#define WSTR 28
#define CHST (MAXBH * WSTR)    // 728 dwords per channel plane

typedef float f32x4 __attribute__((ext_vector_type(4)));

__device__ __forceinline__ void pix2in(float x, float y,
                                       float cs, float sn, float tx, float ty,
                                       float& ix, float& iy)
{
    float gx = (2.0f * x + 1.0f) * (1.0f / (float)WW) - 1.0f;
    float gy = (2.0f * y + 1.0f) * (1.0f / (float)HH) - 1.0f;
    float gxt = cs * gx - sn * gy + tx;
    float gyt = sn * gx + cs * gy + ty;
    ix = ((gxt + 1.0f) * (float)WW - 1.0f) * 0.5f;
    iy = ((gyt + 1.0f) * (float)HH - 1.0f) * 0.5f;
}

__global__ __launch_bounds__(64) void warp_precompute(
    const float* __restrict__ rot, const float* __restrict__ trans,
    const float* __restrict__ scale, float* __restrict__ ws)
{
    int b = threadIdx.x;
    if (b < BB) {
        float r = rot[b];
        float inv_s = 1.0f / scale[b];
        ws[b * 4 + 0] = cosf(r) * inv_s;
        ws[b * 4 + 1] = sinf(r) * inv_s;
        ws[b * 4 + 2] = trans[b * 2 + 0];
        ws[b * 4 + 3] = trans[b * 2 + 1];
    }
}

__global__ __launch_bounds__(256) void warp_wave(
    const float* __restrict__ img, const float* __restrict__ ws,
    float* __restrict__ out)
{
    // 4 waves/block, each with a PRIVATE LDS slice -> no __syncthreads anywhere
    __shared__ __align__(16) float pl[4][CC][MAXBH][WSTR];   // 34944 B -> 4 blocks/CU

    // 16384 blocks; XCD chunk swizzle: each XCD owns 2048 consecutive = 8 whole batches
    const int g    = blockIdx.x;
    const int swz  = (g & 7) * 2048 + (g >> 3);
    const int b    = swz >> 8;            // batch (256 blocks per batch)
    const int bt   = swz & 255;
    const int tid  = threadIdx.x;
    const int wid  = tid >> 6;
    const int lane = tid & 63;
    const int t    = bt * 4 + wid;        // tile 0..1023 (32x32 tiles of 16x16)
    const int oy0  = (t >> 5) * TL;
    const int ox0  = (t & 31) * TL;

    const float4 p = reinterpret_cast<const float4*>(ws)[b];
    const float cs = p.x, sn = p.y, tpx = p.z, tpy = p.w;

    const long plane = (long)HH * WW;
    const float* imb = img + (long)b * CC * plane;
    float* outb      = out + (long)b * CC * plane;

    // ---- in-register bbox: corner (lane&3), 2-step shfl_xor reduce over 4-lane groups ----
    {
        // fallthrough scope
    }
    const float ccx = (float)(ox0 + (lane & 1) * (TL - 1));
    const float ccy = (float)(oy0 + ((lane >> 1) & 1) * (TL - 1));
    float cix, ciy;
    pix2in(ccx, ccy, cs, sn, tpx, tpy, cix, ciy);
    float mnx = fminf(cix, __shfl_xor(cix, 1));
    mnx = fminf(mnx, __shfl_xor(mnx, 2));
    float mxx = fmaxf(cix, __shfl_xor(cix, 1));
    mxx = fmaxf(mxx, __shfl_xor(mxx, 2));
    float mny = fminf(ciy, __shfl_xor(ciy, 1));
    mny = fminf(mny, __shfl_xor(mny, 2));
    float mxy = fmaxf(ciy, __shfl_xor(ciy, 1));
    mxy = fmaxf(mxy, __shfl_xor(mxy, 2));

    const int bx0 = (int)floorf(mnx) - 1;
    const int bx1 = (int)floorf(mxx) + 2;
    const int by0 = (int)floorf(mny) - 1;
    const int by1 = (int)floorf(mxy) + 2;
    const int bw  = bx1 - bx0 + 1;        // <= 26 at scale=1
    const int bh  = by1 - by0 + 1;        // <= 26

    const bool fit      = (bw <= MAXBW) && (bh <= MAXBH);       // wave-uniform
    const bool interior = (bx0 >= 0) && (bx0 + MAXBW - 1 < WW)
                       && (by0 >= 0) && (by1 < HH);

    if (fit) {
        float* pw = &pl[wid][0][0][0];
        // ---- stage: 7 lanes x f32x4 per row, 8 rows per pass, own-wave only ----
        const int rq = lane >> 3;         // 0..7
        const int qc = lane & 7;          // 0..7 (7 active: 28 dwords)
        if (qc < 7) {
            const int xb = qc * 4;
            if (interior) {
                for (int r = rq; r < bh; r += 8) {
                    const float* pr = imb + (long)(by0 + r) * WW + (bx0 + xb);
                    const f32x4 a  = *reinterpret_cast<const f32x4*>(pr);
                    const f32x4 bv = *reinterpret_cast<const f32x4*>(pr + plane);
                    const f32x4 cv = *reinterpret_cast<const f32x4*>(pr + 2 * plane);
                    *reinterpret_cast<f32x4*>(pw + r * WSTR + xb)            = a;
                    *reinterpret_cast<f32x4*>(pw + CHST + r * WSTR + xb)     = bv;
                    *reinterpret_cast<f32x4*>(pw + 2 * CHST + r * WSTR + xb) = cv;
                }
            } else {
                for (int r = rq; r < bh; r += 8) {
                    const int grow = by0 + r;
                    const bool rowok = (grow >= 0) && (grow < HH);
                    const float* pr = imb + (long)grow * WW;
                    f32x4 a = {0.f, 0.f, 0.f, 0.f}, bv = a, cv = a;
                    #pragma unroll
                    for (int k = 0; k < 4; ++k) {
                        const int gcol = bx0 + xb + k;
                        if (rowok && gcol >= 0 && gcol < WW) {
                            a[k]  = pr[gcol];
                            bv[k] = pr[(long)gcol + plane];
                            cv[k] = pr[(long)gcol + 2 * plane];
                        }
                    }
                    *reinterpret_cast<f32x4*>(pw + r * WSTR + xb)            = a;
                    *reinterpret_cast<f32x4*>(pw + CHST + r * WSTR + xb)     = bv;
                    *reinterpret_cast<f32x4*>(pw + 2 * CHST + r * WSTR + xb) = cv;
                }
            }
        }
        // no barrier: same wave produced the data; lgkmcnt ordering suffices

        // ---- compute: lane = 4 rows x 16 stride-1 cols; 4 px/thread ----
        const int ry = lane >> 4;         // 0..3
        const int xp = lane & 15;         // 0..15
        const int ox = ox0 + xp;
        float ix0, iy0;
        pix2in((float)ox, (float)(oy0 + ry), cs, sn, tpx, tpy, ix0, iy0);

        #pragma unroll
        for (int h = 0; h < 4; ++h) {
            const float ix = fmaf((float)(4 * h), -sn, ix0);
            const float iy = fmaf((float)(4 * h),  cs, iy0);
            const float x0f = floorf(ix), y0f = floorf(iy);
            const float wx1 = ix - x0f,  wy1 = iy - y0f;
            const float wx0 = 1.0f - wx1, wy0 = 1.0f - wy1;
            const int x0 = (int)x0f, y0 = (int)y0f;

            float w00 = wy0 * wx0, w01 = wy0 * wx1, w10 = wy1 * wx0, w11 = wy1 * wx1;
            if (!interior) {
                const int x1 = x0 + 1, y1 = y0 + 1;
                const float vx0 = (x0 >= 0 && x0 < WW) ? 1.0f : 0.0f;
                const float vx1 = (x1 >= 0 && x1 < WW) ? 1.0f : 0.0f;
                const float vy0 = (y0 >= 0 && y0 < HH) ? 1.0f : 0.0f;
                const float vy1 = (y1 >= 0 && y1 < HH) ? 1.0f : 0.0f;
                w00 *= vy0 * vx0; w01 *= vy0 * vx1; w10 *= vy1 * vx0; w11 *= vy1 * vx1;
            }

            const int idx = (y0 - by0) * WSTR + (x0 - bx0);   // margin keeps in-slice
            const float* pb = pw + idx;
            const int oy = oy0 + ry + 4 * h;
            const long ob = (long)oy * WW + ox;
            #pragma unroll
            for (int c = 0; c < CC; ++c) {
                const float* pc = pb + c * CHST;
                const float v = w00 * pc[0] + w01 * pc[1]
                              + w10 * pc[WSTR] + w11 * pc[WSTR + 1];
                __builtin_nontemporal_store(v, outb + c * plane + ob);
            }
        }
    } else {
        // ---- fallback: direct global gather (never taken for scale=1) ----
        const int ry = lane >> 4;
        const int xp = lane & 15;
        const int ox = ox0 + xp;
        #pragma unroll
        for (int h = 0; h < 4; ++h) {
            const int oy = oy0 + ry + 4 * h;
            float ix, iy;
            pix2in((float)ox, (float)oy, cs, sn, tpx, tpy, ix, iy);
            const float x0f = floorf(ix), y0f = floorf(iy);
            const float wx1 = ix - x0f,  wy1 = iy - y0f;
            const int x0 = (int)x0f, y0 = (int)y0f;
            const int x1 = x0 + 1,  y1 = y0 + 1;

            const float vx0 = (x0 >= 0 && x0 < WW) ? 1.0f : 0.0f;
            const float vx1 = (x1 >= 0 && x1 < WW) ? 1.0f : 0.0f;
            const float vy0 = (y0 >= 0 && y0 < HH) ? 1.0f : 0.0f;
            const float vy1 = (y1 >= 0 && y1 < HH) ? 1.0f : 0.0f;

            const int x0c = min(max(x0, 0), WW - 1);
            const int x1c = min(max(x1, 0), WW - 1);
            const int y0c = min(max(y0, 0), HH - 1);
            const int y1c = min(max(y1, 0), HH - 1);

            const float w00 = (1.0f - wy1) * (1.0f - wx1) * vy0 * vx0;
            const float w01 = (1.0f - wy1) * wx1          * vy0 * vx1;
            const float w10 = wy1          * (1.0f - wx1) * vy1 * vx0;
            const float w11 = wy1          * wx1          * vy1 * vx1;

            const int o00 = y0c * WW + x0c, o01 = y0c * WW + x1c;
            const int o10 = y1c * WW + x0c, o11 = y1c * WW + x1c;
            const int ob = oy * WW + ox;
            #pragma unroll
            for (int c = 0; c < CC; ++c) {
                const float* pc = imb + (long)c * plane;
                const float v = w00 * pc[o00] + w01 * pc[o01]
                              + w10 * pc[o10] + w11 * pc[o11];
                __builtin_nontemporal_store(v, &outb[(long)c * plane + ob]);
            }
        }
    }
}

extern "C" void kernel_launch(void* const* d_in, const int* in_sizes, int n_in,
                              void* d_out, int out_size, void* d_ws, size_t ws_size,
                              hipStream_t stream) {
    const float* img   = (const float*)d_in[0];
    const float* rot   = (const float*)d_in[1];
    const float* trans = (const float*)d_in[2];
    const float* scale = (const float*)d_in[3];
    float* out = (float*)d_out;
    float* ws  = (float*)d_ws;

    warp_precompute<<<1, 64, 0, stream>>>(rot, trans, scale, ws);
    warp_wave<<<dim3(BB * 256), 256, 0, stream>>>(img, ws, out);
}

// Round 17
// 68.253 us; speedup vs baseline: 1.1708x; 1.1708x over previous
//
#include <hip/hip_runtime.h>
#include <stdint.h>

#define BB 64
#define CC 3
#define HH 512
#define WW 512
#define TILE 32
#define MAXBH 48
#define MAXBW 52
#define PLST 60  // plane row stride (dwords): gcd(60,32)=4 -> 8-bank coverage at vertical angles

typedef float f32x4 __attribute__((ext_vector_type(4)));

__device__ __forceinline__ void pix2in(float x, float y,
                                       float cs, float sn, float tx, float ty,
                                       float& ix, float& iy)
{
    float gx = (2.0f * x + 1.0f) * (1.0f / (float)WW) - 1.0f;
    float gy = (2.0f * y + 1.0f) * (1.0f / (float)HH) - 1.0f;
    float gxt = cs * gx - sn * gy + tx;
    float gyt = sn * gx + cs * gy + ty;
    ix = ((gxt + 1.0f) * (float)WW - 1.0f) * 0.5f;
    iy = ((gyt + 1.0f) * (float)HH - 1.0f) * 0.5f;
}

// ws layout: float prm[64*4] (cs,sn,tx,ty per batch), then uint32 desc[16384]
__global__ __launch_bounds__(256) void warp_setup(
    const float* __restrict__ rot, const float* __restrict__ trans,
    const float* __restrict__ scale, float* __restrict__ ws)
{
    const int i = blockIdx.x * 256 + threadIdx.x;   // 0..16383 = b*256+t
    const int b = i >> 8, t = i & 255;
    const float r = rot[b];
    const float inv_s = 1.0f / scale[b];
    const float cs = cosf(r) * inv_s;
    const float sn = sinf(r) * inv_s;
    const float tx = trans[2 * b], ty = trans[2 * b + 1];
    if (t == 0)
        reinterpret_cast<float4*>(ws)[b] = make_float4(cs, sn, tx, ty);

    const int oy0 = (t >> 4) * TILE;
    const int ox0 = (t & 15) * TILE;
    float ixa, iya, ixb, iyb, ixc, iyc, ixd, iyd;
    pix2in((float)ox0,              (float)oy0,              cs, sn, tx, ty, ixa, iya);
    pix2in((float)(ox0 + TILE - 1), (float)oy0,              cs, sn, tx, ty, ixb, iyb);
    pix2in((float)ox0,              (float)(oy0 + TILE - 1), cs, sn, tx, ty, ixc, iyc);
    pix2in((float)(ox0 + TILE - 1), (float)(oy0 + TILE - 1), cs, sn, tx, ty, ixd, iyd);
    const float minix = fminf(fminf(ixa, ixb), fminf(ixc, ixd));
    const float maxix = fmaxf(fmaxf(ixa, ixb), fmaxf(ixc, ixd));
    const float miniy = fminf(fminf(iya, iyb), fminf(iyc, iyd));
    const float maxiy = fmaxf(fmaxf(iya, iyb), fmaxf(iyc, iyd));
    const int bx0 = (int)floorf(minix) - 1;
    const int bx1 = (int)floorf(maxix) + 2;
    const int by0 = (int)floorf(miniy) - 1;
    const int by1 = (int)floorf(maxiy) + 2;
    int bx0c = bx0 & ~3;
    const int bw = bx1 - bx0c + 1;
    const int bh = by1 - by0 + 1;

    const uint32_t fit      = (bw <= MAXBW && bh <= MAXBH) ? 1u : 0u;
    const uint32_t interior = (bx0c >= 0 && bx1 < WW && by0 >= 0 && by1 < HH) ? 1u : 0u;
    const int bx0s = min(max(bx0c, -2048), 2047);
    const int by0s = min(max(by0,  -2048), 2047);
    const int bhs  = min(bh, 63);
    const uint32_t desc = ((uint32_t)bx0s & 0xFFFu)
                        | (((uint32_t)by0s & 0xFFFu) << 12)
                        | ((uint32_t)bhs << 24)
                        | (fit << 30) | (interior << 31);
    reinterpret_cast<uint32_t*>(ws)[256 + i] = desc;
}

template <bool INTERIOR>
__device__ __forceinline__ void compute_store(
    const float* __restrict__ pl, float* __restrict__ outb,
    int tid, int ox0, int oy0, int bx0c, int by0,
    float cs, float sn, float tpx, float tpy, long plane)
{
    const int ry = tid >> 5;             // 0..15
    const int xp = tid & 31;             // 0..31  (lane stride 1 in x)
    const int ox = ox0 + xp;

    float ix0, iy0;
    pix2in((float)ox, (float)(oy0 + ry), cs, sn, tpx, tpy, ix0, iy0);

    #pragma unroll
    for (int h = 0; h < 2; ++h) {
        // second half: +16 output rows; affine: d(ix)/dy = -sn, d(iy)/dy = +cs
        const float ix = fmaf((float)(16 * h), -sn, ix0);
        const float iy = fmaf((float)(16 * h),  cs, iy0);
        const float x0f = floorf(ix), y0f = floorf(iy);
        const float wx1 = ix - x0f,  wy1 = iy - y0f;
        const float wx0 = 1.0f - wx1, wy0 = 1.0f - wy1;
        const int x0 = (int)x0f, y0 = (int)y0f;

        float w00 = wy0 * wx0, w01 = wy0 * wx1, w10 = wy1 * wx0, w11 = wy1 * wx1;
        if (!INTERIOR) {
            const int x1 = x0 + 1, y1 = y0 + 1;
            const float vx0 = (x0 >= 0 && x0 < WW) ? 1.0f : 0.0f;
            const float vx1 = (x1 >= 0 && x1 < WW) ? 1.0f : 0.0f;
            const float vy0 = (y0 >= 0 && y0 < HH) ? 1.0f : 0.0f;
            const float vy1 = (y1 >= 0 && y1 < HH) ? 1.0f : 0.0f;
            w00 *= vy0 * vx0; w01 *= vy0 * vx1; w10 *= vy1 * vx0; w11 *= vy1 * vx1;
        }

        const int idx = (y0 - by0) * PLST + (x0 - bx0c);   // margin guarantees in-range
        const float* pb = pl + idx;
        const int oy = oy0 + ry + 16 * h;
        const long ob = (long)oy * WW + ox;
        #pragma unroll
        for (int c = 0; c < CC; ++c) {
            const float* pc = pb + c * (MAXBH * PLST);     // channel via byte immediate
            const float v = w00 * pc[0] + w01 * pc[1]
                          + w10 * pc[PLST] + w11 * pc[PLST + 1];
            __builtin_nontemporal_store(v, outb + c * plane + ob);
        }
    }
}

__global__ __launch_bounds__(512) void warp_tiled(
    const float* __restrict__ img, const float* __restrict__ ws,
    float* __restrict__ out)
{
    __shared__ __align__(16) float pl[CC][MAXBH][PLST];   // 34.6 KB, 3 channel planes

    // XCD chunk swizzle: each XCD owns 8 whole batches
    const int g   = blockIdx.x;
    const int swz = (g & 7) * ((BB * 256) / 8) + (g >> 3);
    const int b   = swz >> 8;
    const int t   = swz & 255;
    const int oy0 = (t >> 4) * TILE;
    const int ox0 = (t & 15) * TILE;

    const float4 p = reinterpret_cast<const float4*>(ws)[b];
    const float cs = p.x, sn = p.y, tpx = p.z, tpy = p.w;
    const uint32_t desc = reinterpret_cast<const uint32_t*>(ws)[256 + swz];
    const int  bx0c     = ((int)(desc << 20)) >> 20;
    const int  by0      = ((int)(desc << 8))  >> 20;
    const int  bh       = (desc >> 24) & 63;
    const bool fit      = (desc >> 30) & 1;
    const bool interior = (desc >> 31) & 1;

    const long plane = (long)HH * WW;
    const float* imb = img + (long)b * CC * plane;
    float* outb      = out + (long)b * CC * plane;
    const int tid = threadIdx.x;

    if (fit) {
        const int q  = tid >> 4;          // 0..31 row group
        const int ql = tid & 15;          // 13 active lanes cover 52 cols
        if (ql < 13) {
            const int xb = ql * 4;        // col offset within bbox, 16B-aligned slot
            if (interior && (bx0c + 51 < WW)) {
                for (int r = q; r < bh; r += 32) {
                    const float* pr = imb + (long)(by0 + r) * WW + (bx0c + xb);
                    const f32x4 a = *reinterpret_cast<const f32x4*>(pr);
                    const f32x4 bv = *reinterpret_cast<const f32x4*>(pr + plane);
                    const f32x4 cv = *reinterpret_cast<const f32x4*>(pr + 2 * plane);
                    *reinterpret_cast<f32x4*>(&pl[0][r][xb]) = a;    // contiguous b128
                    *reinterpret_cast<f32x4*>(&pl[1][r][xb]) = bv;
                    *reinterpret_cast<f32x4*>(&pl[2][r][xb]) = cv;
                }
            } else {
                for (int r = q; r < bh; r += 32) {
                    const int grow = by0 + r;
                    const bool rowok = (grow >= 0) && (grow < HH);
                    const float* pr = imb + (long)grow * WW;
                    f32x4 a = {0.f, 0.f, 0.f, 0.f}, bv = a, cv = a;
                    #pragma unroll
                    for (int k = 0; k < 4; ++k) {
                        const int gcol = bx0c + xb + k;
                        if (rowok && gcol >= 0 && gcol < WW) {
                            a[k]  = pr[gcol];
                            bv[k] = pr[(long)gcol + plane];
                            cv[k] = pr[(long)gcol + 2 * plane];
                        }
                    }
                    *reinterpret_cast<f32x4*>(&pl[0][r][xb]) = a;
                    *reinterpret_cast<f32x4*>(&pl[1][r][xb]) = bv;
                    *reinterpret_cast<f32x4*>(&pl[2][r][xb]) = cv;
                }
            }
        }
        __syncthreads();

        if (interior)
            compute_store<true >(&pl[0][0][0], outb, tid, ox0, oy0, bx0c, by0, cs, sn, tpx, tpy, plane);
        else
            compute_store<false>(&pl[0][0][0], outb, tid, ox0, oy0, bx0c, by0, cs, sn, tpx, tpy, plane);
    } else {
        // ---- fallback: direct global gather (never taken for scale=1) ----
        #pragma unroll
        for (int k = 0; k < 2; ++k) {
            const int pidx = tid + k * 512;
            const int py = pidx >> 5;
            const int px = pidx & 31;
            const int ox = ox0 + px, oy = oy0 + py;

            float ix, iy;
            pix2in((float)ox, (float)oy, cs, sn, tpx, tpy, ix, iy);
            const float x0f = floorf(ix), y0f = floorf(iy);
            const float wx1 = ix - x0f,  wy1 = iy - y0f;
            const int x0 = (int)x0f, y0 = (int)y0f;
            const int x1 = x0 + 1,  y1 = y0 + 1;

            const float vx0 = (x0 >= 0 && x0 < WW) ? 1.0f : 0.0f;
            const float vx1 = (x1 >= 0 && x1 < WW) ? 1.0f : 0.0f;
            const float vy0 = (y0 >= 0 && y0 < HH) ? 1.0f : 0.0f;
            const float vy1 = (y1 >= 0 && y1 < HH) ? 1.0f : 0.0f;

            const int x0c = min(max(x0, 0), WW - 1);
            const int x1c = min(max(x1, 0), WW - 1);
            const int y0c = min(max(y0, 0), HH - 1);
            const int y1c = min(max(y1, 0), HH - 1);

            const float w00 = (1.0f - wy1) * (1.0f - wx1) * vy0 * vx0;
            const float w01 = (1.0f - wy1) * wx1          * vy0 * vx1;
            const float w10 = wy1          * (1.0f - wx1) * vy1 * vx0;
            const float w11 = wy1          * wx1          * vy1 * vx1;

            const int o00 = y0c * WW + x0c, o01 = y0c * WW + x1c;
            const int o10 = y1c * WW + x0c, o11 = y1c * WW + x1c;
            const int ob = oy * WW + ox;
            #pragma unroll
            for (int c = 0; c < CC; ++c) {
                const float* pc = imb + (long)c * plane;
                const float v = w00 * pc[o00] + w01 * pc[o01]
                              + w10 * pc[o10] + w11 * pc[o11];
                __builtin_nontemporal_store(v, &outb[(long)c * plane + ob]);
            }
        }
    }
}

extern "C" void kernel_launch(void* const* d_in, const int* in_sizes, int n_in,
                              void* d_out, int out_size, void* d_ws, size_t ws_size,
                              hipStream_t stream) {
    const float* img   = (const float*)d_in[0];
    const float* rot   = (const float*)d_in[1];
    const float* trans = (const float*)d_in[2];
    const float* scale = (const float*)d_in[3];
    float* out = (float*)d_out;
    float* ws  = (float*)d_ws;

    warp_setup<<<dim3(BB), 256, 0, stream>>>(rot, trans, scale, ws);
    warp_tiled<<<dim3(BB * 256), 512, 0, stream>>>(img, ws, out);
}

// Round 18
// 67.960 us; speedup vs baseline: 1.1759x; 1.0043x over previous
//
#include <hip/hip_runtime.h>
#include <stdint.h>

#define BB 64
#define CC 3
#define HH 512
#define WW 512
#define TILE 32
#define MAXBH 48
#define MAXBW 52
#define RSD 64                // row stride (dwords): 4 rows = 1KB = one wave DMA instr
#define CHSTD (MAXBH * RSD)   // 3072 dwords per channel plane
// LDS layout: logical chunk c (16B) of row r lives at slot c^(r&15); DMA writes linearly,
// so the global SOURCE column is pre-swizzled (per-lane src is allowed; dest is uniform+lane*16).

typedef float f32x4 __attribute__((ext_vector_type(4)));

__device__ __forceinline__ void gload_lds16(const float* src, float* lds)
{
    __builtin_amdgcn_global_load_lds(
        (const __attribute__((address_space(1))) unsigned int*)src,
        (__attribute__((address_space(3))) unsigned int*)lds,
        16, 0, 0);
}

__device__ __forceinline__ void pix2in(float x, float y,
                                       float cs, float sn, float tx, float ty,
                                       float& ix, float& iy)
{
    float gx = (2.0f * x + 1.0f) * (1.0f / (float)WW) - 1.0f;
    float gy = (2.0f * y + 1.0f) * (1.0f / (float)HH) - 1.0f;
    float gxt = cs * gx - sn * gy + tx;
    float gyt = sn * gx + cs * gy + ty;
    ix = ((gxt + 1.0f) * (float)WW - 1.0f) * 0.5f;
    iy = ((gyt + 1.0f) * (float)HH - 1.0f) * 0.5f;
}

// ws layout: float prm[64*4] (cs,sn,tx,ty per batch), then uint32 desc[16384]
__global__ __launch_bounds__(256) void warp_setup(
    const float* __restrict__ rot, const float* __restrict__ trans,
    const float* __restrict__ scale, float* __restrict__ ws)
{
    const int i = blockIdx.x * 256 + threadIdx.x;   // 0..16383 = b*256+t
    const int b = i >> 8, t = i & 255;
    const float r = rot[b];
    const float inv_s = 1.0f / scale[b];
    const float cs = cosf(r) * inv_s;
    const float sn = sinf(r) * inv_s;
    const float tx = trans[2 * b], ty = trans[2 * b + 1];
    if (t == 0)
        reinterpret_cast<float4*>(ws)[b] = make_float4(cs, sn, tx, ty);

    const int oy0 = (t >> 4) * TILE;
    const int ox0 = (t & 15) * TILE;
    float ixa, iya, ixb, iyb, ixc, iyc, ixd, iyd;
    pix2in((float)ox0,              (float)oy0,              cs, sn, tx, ty, ixa, iya);
    pix2in((float)(ox0 + TILE - 1), (float)oy0,              cs, sn, tx, ty, ixb, iyb);
    pix2in((float)ox0,              (float)(oy0 + TILE - 1), cs, sn, tx, ty, ixc, iyc);
    pix2in((float)(ox0 + TILE - 1), (float)(oy0 + TILE - 1), cs, sn, tx, ty, ixd, iyd);
    const float minix = fminf(fminf(ixa, ixb), fminf(ixc, ixd));
    const float maxix = fmaxf(fmaxf(ixa, ixb), fmaxf(ixc, ixd));
    const float miniy = fminf(fminf(iya, iyb), fminf(iyc, iyd));
    const float maxiy = fmaxf(fmaxf(iya, iyb), fmaxf(iyc, iyd));
    const int bx0 = (int)floorf(minix) - 1;
    const int bx1 = (int)floorf(maxix) + 2;
    const int by0 = (int)floorf(miniy) - 1;
    const int by1 = (int)floorf(maxiy) + 2;
    int bx0c = bx0 & ~3;
    const int bw = bx1 - bx0c + 1;
    const int bh = by1 - by0 + 1;

    const uint32_t fit      = (bw <= MAXBW && bh <= MAXBH) ? 1u : 0u;
    const uint32_t interior = (bx0c >= 0 && bx1 < WW && by0 >= 0 && by1 < HH) ? 1u : 0u;
    const int bx0s = min(max(bx0c, -2048), 2047);
    const int by0s = min(max(by0,  -2048), 2047);
    const int bhs  = min(bh, 63);
    const uint32_t desc = ((uint32_t)bx0s & 0xFFFu)
                        | (((uint32_t)by0s & 0xFFFu) << 12)
                        | ((uint32_t)bhs << 24)
                        | (fit << 30) | (interior << 31);
    reinterpret_cast<uint32_t*>(ws)[256 + i] = desc;
}

template <bool INTERIOR>
__device__ __forceinline__ void compute_store(
    const float* __restrict__ pl, float* __restrict__ outb,
    int tid, int ox0, int oy0, int bx0c, int by0,
    float cs, float sn, float tpx, float tpy, long plane)
{
    const int ry = tid >> 5;             // 0..15
    const int xp = tid & 31;             // 0..31 (lane stride 1 in x)
    const int ox = ox0 + xp;

    float ix0, iy0;
    pix2in((float)ox, (float)(oy0 + ry), cs, sn, tpx, tpy, ix0, iy0);

    #pragma unroll
    for (int h = 0; h < 2; ++h) {
        const float ix = fmaf((float)(16 * h), -sn, ix0);   // +16 rows: d/dy = (-sn, +cs)
        const float iy = fmaf((float)(16 * h),  cs, iy0);
        const float x0f = floorf(ix), y0f = floorf(iy);
        const float wx1 = ix - x0f,  wy1 = iy - y0f;
        const float wx0 = 1.0f - wx1, wy0 = 1.0f - wy1;
        const int x0 = (int)x0f, y0 = (int)y0f;

        float w00 = wy0 * wx0, w01 = wy0 * wx1, w10 = wy1 * wx0, w11 = wy1 * wx1;
        if (!INTERIOR) {
            const int x1 = x0 + 1, y1 = y0 + 1;
            const float vx0 = (x0 >= 0 && x0 < WW) ? 1.0f : 0.0f;
            const float vx1 = (x1 >= 0 && x1 < WW) ? 1.0f : 0.0f;
            const float vy0 = (y0 >= 0 && y0 < HH) ? 1.0f : 0.0f;
            const float vy1 = (y1 >= 0 && y1 < HH) ? 1.0f : 0.0f;
            w00 *= vy0 * vx0; w01 *= vy0 * vx1; w10 *= vy1 * vx0; w11 *= vy1 * vx1;
        }

        const int ly0 = y0 - by0;              // margin guarantees in-range
        const int ly1 = ly0 + 1;
        const int lx0 = x0 - bx0c;
        const int lx1 = lx0 + 1;
        const int k0 = ly0 & 15, k1 = ly1 & 15;
        const int s00 = (ly0 << 6) + ((((lx0 >> 2) ^ k0) << 2) | (lx0 & 3));
        const int s01 = (ly0 << 6) + ((((lx1 >> 2) ^ k0) << 2) | (lx1 & 3));
        const int s10 = (ly1 << 6) + ((((lx0 >> 2) ^ k1) << 2) | (lx0 & 3));
        const int s11 = (ly1 << 6) + ((((lx1 >> 2) ^ k1) << 2) | (lx1 & 3));

        const int oy = oy0 + ry + 16 * h;
        const long ob = (long)oy * WW + ox;
        #pragma unroll
        for (int c = 0; c < CC; ++c) {
            const float* pc = pl + c * CHSTD;   // channel via byte immediate (<= 24KB)
            const float v = w00 * pc[s00] + w01 * pc[s01]
                          + w10 * pc[s10] + w11 * pc[s11];
            __builtin_nontemporal_store(v, outb + c * plane + ob);
        }
    }
}

__global__ __launch_bounds__(512) void warp_tiled(
    const float* __restrict__ img, const float* __restrict__ ws,
    float* __restrict__ out)
{
    __shared__ __align__(16) float pl[CC][MAXBH][RSD];   // 36.9 KB -> 4 blocks/CU

    // XCD chunk swizzle: each XCD owns 8 whole batches
    const int g   = blockIdx.x;
    const int swz = (g & 7) * ((BB * 256) / 8) + (g >> 3);
    const int b   = swz >> 8;
    const int t   = swz & 255;
    const int oy0 = (t >> 4) * TILE;
    const int ox0 = (t & 15) * TILE;

    const float4 p = reinterpret_cast<const float4*>(ws)[b];
    const float cs = p.x, sn = p.y, tpx = p.z, tpy = p.w;
    const uint32_t desc = reinterpret_cast<const uint32_t*>(ws)[256 + swz];
    const int  bx0c     = ((int)(desc << 20)) >> 20;
    const int  by0      = ((int)(desc << 8))  >> 20;
    const int  bh       = (desc >> 24) & 63;
    const bool fit      = (desc >> 30) & 1;
    const bool interior = (desc >> 31) & 1;

    const long plane = (long)HH * WW;
    const float* imb = img + (long)b * CC * plane;
    float* outb      = out + (long)b * CC * plane;
    const int tid = threadIdx.x;

    if (fit) {
        const bool dma = interior && (bx0c + 63 < WW);   // DMA reads 64 cols; all in-image rows
        if (dma) {
            // ---- stage via global_load_lds: 1 wave-instr = 4 rows x 64 dwords ----
            const int wid   = tid >> 6;          // 0..7
            const int rin   = (tid & 63) >> 4;   // row within 4-row block
            const int chunk = tid & 15;          // 16B chunk slot this lane fills
            const int rbmax = (bh + 3) >> 2;
            for (int ch = 0; ch < CC; ++ch) {
                const float* pc = imb + (long)ch * plane;
                for (int rb = wid; rb < rbmax; rb += 8) {
                    const int r    = rb * 4 + rin;
                    const int grow = min(by0 + r, HH - 1);   // clamp tail rows (never read)
                    const int sch  = chunk ^ (r & 15);       // pre-swizzled source chunk
                    const float* src = pc + (long)grow * WW + bx0c + sch * 4;
                    gload_lds16(src, &pl[ch][rb * 4][0]);    // dest uniform + lane*16B
                }
            }
        } else {
            // ---- masked reg-staging (edge tiles), writing the same swizzled slots ----
            const int q  = tid >> 4;          // 0..31 row group
            const int ql = tid & 15;          // 13 active lanes cover 52 cols
            if (ql < 13) {
                const int xb = ql * 4;
                for (int r = q; r < bh; r += 32) {
                    const int grow = by0 + r;
                    const bool rowok = (grow >= 0) && (grow < HH);
                    const float* pr = imb + (long)grow * WW;
                    f32x4 a = {0.f, 0.f, 0.f, 0.f}, bv = a, cv = a;
                    #pragma unroll
                    for (int k = 0; k < 4; ++k) {
                        const int gcol = bx0c + xb + k;
                        if (rowok && gcol >= 0 && gcol < WW) {
                            a[k]  = pr[gcol];
                            bv[k] = pr[(long)gcol + plane];
                            cv[k] = pr[(long)gcol + 2 * plane];
                        }
                    }
                    const int slot4 = (ql ^ (r & 15)) << 2;
                    *reinterpret_cast<f32x4*>(&pl[0][r][slot4]) = a;
                    *reinterpret_cast<f32x4*>(&pl[1][r][slot4]) = bv;
                    *reinterpret_cast<f32x4*>(&pl[2][r][slot4]) = cv;
                }
            }
        }
        __syncthreads();   // drains vmcnt (incl. global_load_lds) + lgkmcnt

        if (interior)
            compute_store<true >(&pl[0][0][0], outb, tid, ox0, oy0, bx0c, by0, cs, sn, tpx, tpy, plane);
        else
            compute_store<false>(&pl[0][0][0], outb, tid, ox0, oy0, bx0c, by0, cs, sn, tpx, tpy, plane);
    } else {
        // ---- fallback: direct global gather (never taken for scale=1) ----
        #pragma unroll
        for (int k = 0; k < 2; ++k) {
            const int pidx = tid + k * 512;
            const int py = pidx >> 5;
            const int px = pidx & 31;
            const int ox = ox0 + px, oy = oy0 + py;

            float ix, iy;
            pix2in((float)ox, (float)oy, cs, sn, tpx, tpy, ix, iy);
            const float x0f = floorf(ix), y0f = floorf(iy);
            const float wx1 = ix - x0f,  wy1 = iy - y0f;
            const int x0 = (int)x0f, y0 = (int)y0f;
            const int x1 = x0 + 1,  y1 = y0 + 1;

            const float vx0 = (x0 >= 0 && x0 < WW) ? 1.0f : 0.0f;
            const float vx1 = (x1 >= 0 && x1 < WW) ? 1.0f : 0.0f;
            const float vy0 = (y0 >= 0 && y0 < HH) ? 1.0f : 0.0f;
            const float vy1 = (y1 >= 0 && y1 < HH) ? 1.0f : 0.0f;

            const int x0c = min(max(x0, 0), WW - 1);
            const int x1c = min(max(x1, 0), WW - 1);
            const int y0c = min(max(y0, 0), HH - 1);
            const int y1c = min(max(y1, 0), HH - 1);

            const float w00 = (1.0f - wy1) * (1.0f - wx1) * vy0 * vx0;
            const float w01 = (1.0f - wy1) * wx1          * vy0 * vx1;
            const float w10 = wy1          * (1.0f - wx1) * vy1 * vx0;
            const float w11 = wy1          * wx1          * vy1 * vx1;

            const int o00 = y0c * WW + x0c, o01 = y0c * WW + x1c;
            const int o10 = y1c * WW + x0c, o11 = y1c * WW + x1c;
            const int ob = oy * WW + ox;
            #pragma unroll
            for (int c = 0; c < CC; ++c) {
                const float* pc = imb + (long)c * plane;
                const float v = w00 * pc[o00] + w01 * pc[o01]
                              + w10 * pc[o10] + w11 * pc[o11];
                __builtin_nontemporal_store(v, &outb[(long)c * plane + ob]);
            }
        }
    }
}

extern "C" void kernel_launch(void* const* d_in, const int* in_sizes, int n_in,
                              void* d_out, int out_size, void* d_ws, size_t ws_size,
                              hipStream_t stream) {
    const float* img   = (const float*)d_in[0];
    const float* rot   = (const float*)d_in[1];
    const float* trans = (const float*)d_in[2];
    const float* scale = (const float*)d_in[3];
    float* out = (float*)d_out;
    float* ws  = (float*)d_ws;

    warp_setup<<<dim3(BB), 256, 0, stream>>>(rot, trans, scale, ws);
    warp_tiled<<<dim3(BB * 256), 512, 0, stream>>>(img, ws, out);
}

// Round 19
// 67.517 us; speedup vs baseline: 1.1836x; 1.0066x over previous
//
#include <hip/hip_runtime.h>
#include <stdint.h>

#define BB 64
#define CC 3
#define HH 512
#define WW 512
#define TILE 32
#define MAXBH 48
#define MAXBW 52
#define PLST 56  // plane row stride (dwords): best measured (R13, 67.26us)

typedef float f32x4 __attribute__((ext_vector_type(4)));

__device__ __forceinline__ void pix2in(float x, float y,
                                       float cs, float sn, float tx, float ty,
                                       float& ix, float& iy)
{
    float gx = (2.0f * x + 1.0f) * (1.0f / (float)WW) - 1.0f;
    float gy = (2.0f * y + 1.0f) * (1.0f / (float)HH) - 1.0f;
    float gxt = cs * gx - sn * gy + tx;
    float gyt = sn * gx + cs * gy + ty;
    ix = ((gxt + 1.0f) * (float)WW - 1.0f) * 0.5f;
    iy = ((gyt + 1.0f) * (float)HH - 1.0f) * 0.5f;
}

// ws layout: float prm[64*4] (cs,sn,tx,ty per batch), then uint32 desc[16384]
__global__ __launch_bounds__(256) void warp_setup(
    const float* __restrict__ rot, const float* __restrict__ trans,
    const float* __restrict__ scale, float* __restrict__ ws)
{
    const int i = blockIdx.x * 256 + threadIdx.x;   // 0..16383 = b*256+t
    const int b = i >> 8, t = i & 255;
    const float r = rot[b];
    const float inv_s = 1.0f / scale[b];
    const float cs = cosf(r) * inv_s;
    const float sn = sinf(r) * inv_s;
    const float tx = trans[2 * b], ty = trans[2 * b + 1];
    if (t == 0)
        reinterpret_cast<float4*>(ws)[b] = make_float4(cs, sn, tx, ty);

    const int oy0 = (t >> 4) * TILE;
    const int ox0 = (t & 15) * TILE;
    float ixa, iya, ixb, iyb, ixc, iyc, ixd, iyd;
    pix2in((float)ox0,              (float)oy0,              cs, sn, tx, ty, ixa, iya);
    pix2in((float)(ox0 + TILE - 1), (float)oy0,              cs, sn, tx, ty, ixb, iyb);
    pix2in((float)ox0,              (float)(oy0 + TILE - 1), cs, sn, tx, ty, ixc, iyc);
    pix2in((float)(ox0 + TILE - 1), (float)(oy0 + TILE - 1), cs, sn, tx, ty, ixd, iyd);
    const float minix = fminf(fminf(ixa, ixb), fminf(ixc, ixd));
    const float maxix = fmaxf(fmaxf(ixa, ixb), fmaxf(ixc, ixd));
    const float miniy = fminf(fminf(iya, iyb), fminf(iyc, iyd));
    const float maxiy = fmaxf(fmaxf(iya, iyb), fmaxf(iyc, iyd));
    const int bx0 = (int)floorf(minix) - 1;
    const int bx1 = (int)floorf(maxix) + 2;
    const int by0 = (int)floorf(miniy) - 1;
    const int by1 = (int)floorf(maxiy) + 2;
    int bx0c = bx0 & ~3;
    const int bw = bx1 - bx0c + 1;
    const int bh = by1 - by0 + 1;

    const uint32_t fit      = (bw <= MAXBW && bh <= MAXBH) ? 1u : 0u;
    const uint32_t interior = (bx0c >= 0 && bx1 < WW && by0 >= 0 && by1 < HH) ? 1u : 0u;
    const int bx0s = min(max(bx0c, -2048), 2047);
    const int by0s = min(max(by0,  -2048), 2047);
    const int bhs  = min(bh, 63);
    const uint32_t desc = ((uint32_t)bx0s & 0xFFFu)
                        | (((uint32_t)by0s & 0xFFFu) << 12)
                        | ((uint32_t)bhs << 24)
                        | (fit << 30) | (interior << 31);
    reinterpret_cast<uint32_t*>(ws)[256 + i] = desc;
}

template <bool INTERIOR>
__device__ __forceinline__ void compute_store(
    const float* __restrict__ pl, float* __restrict__ outb,
    int tid, int ox0, int oy0, int bx0c, int by0,
    float cs, float sn, float tpx, float tpy, long plane)
{
    const int ry = tid >> 5;             // 0..15
    const int xp = tid & 31;             // 0..31  (lane stride 1 in x)
    const int ox = ox0 + xp;

    float ix0, iy0;
    pix2in((float)ox, (float)(oy0 + ry), cs, sn, tpx, tpy, ix0, iy0);

    #pragma unroll
    for (int h = 0; h < 2; ++h) {
        // second half: +16 output rows; affine: d(ix)/dy = -sn, d(iy)/dy = +cs
        const float ix = fmaf((float)(16 * h), -sn, ix0);
        const float iy = fmaf((float)(16 * h),  cs, iy0);
        const float x0f = floorf(ix), y0f = floorf(iy);
        const float wx1 = ix - x0f,  wy1 = iy - y0f;
        const float wx0 = 1.0f - wx1, wy0 = 1.0f - wy1;
        const int x0 = (int)x0f, y0 = (int)y0f;

        float w00 = wy0 * wx0, w01 = wy0 * wx1, w10 = wy1 * wx0, w11 = wy1 * wx1;
        if (!INTERIOR) {
            const int x1 = x0 + 1, y1 = y0 + 1;
            const float vx0 = (x0 >= 0 && x0 < WW) ? 1.0f : 0.0f;
            const float vx1 = (x1 >= 0 && x1 < WW) ? 1.0f : 0.0f;
            const float vy0 = (y0 >= 0 && y0 < HH) ? 1.0f : 0.0f;
            const float vy1 = (y1 >= 0 && y1 < HH) ? 1.0f : 0.0f;
            w00 *= vy0 * vx0; w01 *= vy0 * vx1; w10 *= vy1 * vx0; w11 *= vy1 * vx1;
        }

        const int idx = (y0 - by0) * PLST + (x0 - bx0c);   // margin guarantees in-range
        const float* pb = pl + idx;
        const int oy = oy0 + ry + 16 * h;
        const long ob = (long)oy * WW + ox;
        #pragma unroll
        for (int c = 0; c < CC; ++c) {
            const float* pc = pb + c * (MAXBH * PLST);     // channel via byte immediate
            const float v = w00 * pc[0] + w01 * pc[1]
                          + w10 * pc[PLST] + w11 * pc[PLST + 1];
            __builtin_nontemporal_store(v, outb + c * plane + ob);
        }
    }
}

__global__ __launch_bounds__(512) void warp_tiled(
    const float* __restrict__ img, const float* __restrict__ ws,
    float* __restrict__ out)
{
    __shared__ __align__(16) float pl[CC][MAXBH][PLST];   // 32.3 KB, 3 channel planes

    // XCD chunk swizzle: each XCD owns 8 whole batches
    const int g   = blockIdx.x;
    const int swz = (g & 7) * ((BB * 256) / 8) + (g >> 3);
    const int b   = swz >> 8;
    const int t   = swz & 255;
    const int oy0 = (t >> 4) * TILE;
    const int ox0 = (t & 15) * TILE;

    const float4 p = reinterpret_cast<const float4*>(ws)[b];
    const float cs = p.x, sn = p.y, tpx = p.z, tpy = p.w;
    const uint32_t desc = reinterpret_cast<const uint32_t*>(ws)[256 + swz];
    const int  bx0c     = ((int)(desc << 20)) >> 20;
    const int  by0      = ((int)(desc << 8))  >> 20;
    const int  bh       = (desc >> 24) & 63;
    const bool fit      = (desc >> 30) & 1;
    const bool interior = (desc >> 31) & 1;

    const long plane = (long)HH * WW;
    const float* imb = img + (long)b * CC * plane;
    float* outb      = out + (long)b * CC * plane;
    const int tid = threadIdx.x;

    if (fit) {
        const int q  = tid >> 4;          // 0..31 row group
        const int ql = tid & 15;          // 13 active lanes cover 52 cols
        if (ql < 13) {
            const int xb = ql * 4;        // col offset within bbox, 16B-aligned slot
            if (interior && (bx0c + 51 < WW)) {
                for (int r = q; r < bh; r += 32) {
                    const float* pr = imb + (long)(by0 + r) * WW + (bx0c + xb);
                    const f32x4 a = *reinterpret_cast<const f32x4*>(pr);
                    const f32x4 bv = *reinterpret_cast<const f32x4*>(pr + plane);
                    const f32x4 cv = *reinterpret_cast<const f32x4*>(pr + 2 * plane);
                    *reinterpret_cast<f32x4*>(&pl[0][r][xb]) = a;    // contiguous b128
                    *reinterpret_cast<f32x4*>(&pl[1][r][xb]) = bv;
                    *reinterpret_cast<f32x4*>(&pl[2][r][xb]) = cv;
                }
            } else {
                for (int r = q; r < bh; r += 32) {
                    const int grow = by0 + r;
                    const bool rowok = (grow >= 0) && (grow < HH);
                    const float* pr = imb + (long)grow * WW;
                    f32x4 a = {0.f, 0.f, 0.f, 0.f}, bv = a, cv = a;
                    #pragma unroll
                    for (int k = 0; k < 4; ++k) {
                        const int gcol = bx0c + xb + k;
                        if (rowok && gcol >= 0 && gcol < WW) {
                            a[k]  = pr[gcol];
                            bv[k] = pr[(long)gcol + plane];
                            cv[k] = pr[(long)gcol + 2 * plane];
                        }
                    }
                    *reinterpret_cast<f32x4*>(&pl[0][r][xb]) = a;
                    *reinterpret_cast<f32x4*>(&pl[1][r][xb]) = bv;
                    *reinterpret_cast<f32x4*>(&pl[2][r][xb]) = cv;
                }
            }
        }
        __syncthreads();

        if (interior)
            compute_store<true >(&pl[0][0][0], outb, tid, ox0, oy0, bx0c, by0, cs, sn, tpx, tpy, plane);
        else
            compute_store<false>(&pl[0][0][0], outb, tid, ox0, oy0, bx0c, by0, cs, sn, tpx, tpy, plane);
    } else {
        // ---- fallback: direct global gather (never taken for scale=1) ----
        #pragma unroll
        for (int k = 0; k < 2; ++k) {
            const int pidx = tid + k * 512;
            const int py = pidx >> 5;
            const int px = pidx & 31;
            const int ox = ox0 + px, oy = oy0 + py;

            float ix, iy;
            pix2in((float)ox, (float)oy, cs, sn, tpx, tpy, ix, iy);
            const float x0f = floorf(ix), y0f = floorf(iy);
            const float wx1 = ix - x0f,  wy1 = iy - y0f;
            const int x0 = (int)x0f, y0 = (int)y0f;
            const int x1 = x0 + 1,  y1 = y0 + 1;

            const float vx0 = (x0 >= 0 && x0 < WW) ? 1.0f : 0.0f;
            const float vx1 = (x1 >= 0 && x1 < WW) ? 1.0f : 0.0f;
            const float vy0 = (y0 >= 0 && y0 < HH) ? 1.0f : 0.0f;
            const float vy1 = (y1 >= 0 && y1 < HH) ? 1.0f : 0.0f;

            const int x0c = min(max(x0, 0), WW - 1);
            const int x1c = min(max(x1, 0), WW - 1);
            const int y0c = min(max(y0, 0), HH - 1);
            const int y1c = min(max(y1, 0), HH - 1);

            const float w00 = (1.0f - wy1) * (1.0f - wx1) * vy0 * vx0;
            const float w01 = (1.0f - wy1) * wx1          * vy0 * vx1;
            const float w10 = wy1          * (1.0f - wx1) * vy1 * vx0;
            const float w11 = wy1          * wx1          * vy1 * vx1;

            const int o00 = y0c * WW + x0c, o01 = y0c * WW + x1c;
            const int o10 = y1c * WW + x0c, o11 = y1c * WW + x1c;
            const int ob = oy * WW + ox;
            #pragma unroll
            for (int c = 0; c < CC; ++c) {
                const float* pc = imb + (long)c * plane;
                const float v = w00 * pc[o00] + w01 * pc[o01]
                              + w10 * pc[o10] + w11 * pc[o11];
                __builtin_nontemporal_store(v, &outb[(long)c * plane + ob]);
            }
        }
    }
}

extern "C" void kernel_launch(void* const* d_in, const int* in_sizes, int n_in,
                              void* d_out, int out_size, void* d_ws, size_t ws_size,
                              hipStream_t stream) {
    const float* img   = (const float*)d_in[0];
    const float* rot   = (const float*)d_in[1];
    const float* trans = (const float*)d_in[2];
    const float* scale = (const float*)d_in[3];
    float* out = (float*)d_out;
    float* ws  = (float*)d_ws;

    warp_setup<<<dim3(BB), 256, 0, stream>>>(rot, trans, scale, ws);
    warp_tiled<<<dim3(BB * 256), 512, 0, stream>>>(img, ws, out);
}